// Round 6
// baseline (46.115 us; speedup 1.0000x reference)
//
#include <hip/hip_runtime.h>

#define H 32
#define C 64
#define K 15
#define SIGMA 0.3f
#define WAVES 4
#define PAIRS_PER_WAVE 7

__global__ __launch_bounds__(256) void kpconv_kernel(
    const float* __restrict__ q_pts,
    const float* __restrict__ s_pts,
    const float* __restrict__ s_feats,
    const int*   __restrict__ inds,
    const float* __restrict__ weights,
    const float* __restrict__ kpts,
    float*       __restrict__ out,
    int N)
{
    __shared__ float2 list[WAVES][2][32];   // 2 KB, wave-private slices

    const int tid  = threadIdx.x;
    const int wave = tid >> 6;
    const int lane = tid & 63;
    const int half = lane >> 5;         // which query of the wave's pair
    const int hl   = lane & 31;         // neighbor slot / channel-pair slot

    // wave-uniform kernel points -> SGPRs via s_load (amortized over all pairs)
    float kp[K * 3];
    #pragma unroll
    for (int i = 0; i < K * 3; ++i) kp[i] = kpts[i];

    const int nPairs = (N + 1) >> 1;
    const int waveId = blockIdx.x * WAVES + wave;
    const int stride = gridDim.x * WAVES;

    int pair = waveId;
    if (pair >= nPairs) return;

    // ---- pipeline prologue: stage loads for first pair ----
    int  mC   = pair * 2 + half;
    int  idxC = (mC < N) ? inds[mC * H + hl] : -1;
    bool okC  = (idxC >= 0) && (idxC < N);
    {   // clamp for safe speculative gather
        const int ia = okC ? idxC : 0;
        (void)ia;
    }
    const int ia0 = okC ? idxC : 0;
    float sxC = s_pts[ia0 * 3 + 0], syC = s_pts[ia0 * 3 + 1], szC = s_pts[ia0 * 3 + 2];
    float qxC = 0.f, qyC = 0.f, qzC = 0.f;
    if (mC < N) { qxC = q_pts[mC * 3 + 0]; qyC = q_pts[mC * 3 + 1]; qzC = q_pts[mC * 3 + 2]; }

    while (true) {
        const int  pairN   = pair + stride;
        const bool hasNext = pairN < nPairs;
        const int  mN      = pairN * 2 + half;

        // ---- issue next pair's index load early (hidden under argmin) ----
        int idxN = -1;
        if (hasNext && mN < N) idxN = inds[mN * H + hl];

        // ---- Phase A: argmin kernel point + influence (math unchanged) ----
        float infl = 0.0f; int packed = 0;
        if (okC && (mC < N)) {
            const float nx = sxC - qxC, ny = syC - qyC, nz = szC - qzC;
            float best = 1e30f; int kbest = 0;
            #pragma unroll
            for (int k = 0; k < K; ++k) {
                const float dx = nx - kp[k * 3 + 0];
                const float dy = ny - kp[k * 3 + 1];
                const float dz = nz - kp[k * 3 + 2];
                const float d2 = dx * dx + dy * dy + dz * dz;
                if (d2 < best) { best = d2; kbest = k; }
            }
            infl = 1.0f - sqrtf(best) / SIGMA;
            if (infl < 0.0f) infl = 0.0f;
            packed = idxC | (kbest << 20);
        }

        // ---- compact actives into wave-private LDS list ----
        const unsigned long long ball = __ballot(infl > 0.0f);
        const unsigned int maskH = half ? (unsigned int)(ball >> 32)
                                        : (unsigned int)(ball & 0xFFFFFFFFu);
        const int rank = __popc(maskH & ((1u << hl) - 1u));
        if (infl > 0.0f)
            list[wave][half][rank] = make_float2(__int_as_float(packed), infl);
        const int cnt = __popc(maskH);
        // same-wave LDS RAW: DS pipe is in-order per wave; no barrier needed.

        // ---- issue next pair's point loads (fly under Phase B) ----
        float sxN = 0.f, syN = 0.f, szN = 0.f, qxN = 0.f, qyN = 0.f, qzN = 0.f;
        bool  okN = false;
        if (hasNext) {
            okN = (idxN >= 0) && (idxN < N);
            const int ib = okN ? idxN : 0;
            sxN = s_pts[ib * 3 + 0]; syN = s_pts[ib * 3 + 1]; szN = s_pts[ib * 3 + 2];
            if (mN < N) { qxN = q_pts[mN * 3 + 0]; qyN = q_pts[mN * 3 + 1]; qzN = q_pts[mN * 3 + 2]; }
        }

        // ---- Phase B: half-wave per query, float2 channels, 2 pops/iter ----
        float2 acc = make_float2(0.0f, 0.0f);
        const float2* wrows = (const float2*)weights;
        for (int i = 0; i < cnt; i += 2) {
            const float4 pf = *(const float4*)&list[wave][half][i];  // 16B aligned
            const int   p0   = __float_as_int(pf.x);
            const float f0   = pf.y;
            const bool  has1 = (i + 1) < cnt;
            const int   p1   = has1 ? __float_as_int(pf.z) : 0;   // row 0: cached
            const float f1   = has1 ? pf.w : 0.0f;
            const float2 a0 = ((const float2*)(s_feats + (size_t)(p0 & 0xFFFFF) * C))[hl];
            const float2 w0 = wrows[(p0 >> 20) * (C / 2) + hl];
            const float2 a1 = ((const float2*)(s_feats + (size_t)(p1 & 0xFFFFF) * C))[hl];
            const float2 w1 = wrows[(p1 >> 20) * (C / 2) + hl];
            acc.x += a0.x * w0.x * f0;
            acc.y += a0.y * w0.y * f0;
            acc.x += a1.x * w1.x * f1;
            acc.y += a1.y * w1.y * f1;
        }
        if (mC < N)
            *(float2*)(out + (size_t)mC * C + hl * 2) = acc;   // 256B per half-wave

        if (!hasNext) break;
        // ---- rotate pipeline registers ----
        pair = pairN; mC = mN; idxC = idxN; okC = okN;
        sxC = sxN; syC = syN; szC = szN;
        qxC = qxN; qyC = qyN; qzC = qzN;
    }
}

extern "C" void kernel_launch(void* const* d_in, const int* in_sizes, int n_in,
                              void* d_out, int out_size, void* d_ws, size_t ws_size,
                              hipStream_t stream) {
    const float* q_pts   = (const float*)d_in[0];
    const float* s_pts   = (const float*)d_in[1];
    const float* s_feats = (const float*)d_in[2];
    const int*   inds    = (const int*)d_in[3];
    const float* weights = (const float*)d_in[4];
    const float* kpts    = (const float*)d_in[5];
    float* out = (float*)d_out;

    const int N = in_sizes[0] / 3;               // q_pts is (N,3)
    const int nPairs = (N + 1) / 2;
    int blocks = (nPairs + WAVES * PAIRS_PER_WAVE - 1) / (WAVES * PAIRS_PER_WAVE);
    if (blocks < 1) blocks = 1;
    kpconv_kernel<<<blocks, 256, 0, stream>>>(q_pts, s_pts, s_feats, inds,
                                              weights, kpts, out, N);
}

// Round 7
// 33.363 us; speedup vs baseline: 1.3822x; 1.3822x over previous
//
#include <hip/hip_runtime.h>

#define H 32
#define C 64
#define K 15
#define SIGMA 0.3f
#define WAVES 4
#define QPW 4    // queries per wave

__global__ __launch_bounds__(256) void kpconv_kernel(
    const float* __restrict__ q_pts,
    const float* __restrict__ s_pts,
    const float* __restrict__ s_feats,
    const int*   __restrict__ inds,
    const float* __restrict__ weights,
    const float* __restrict__ kpts,
    float*       __restrict__ out,
    int N)
{
    // padded row (34 float2 = 272 B): q-rows stay 16B-aligned, banks spread
    __shared__ float2 list[WAVES][QPW][34];   // 4.25 KB

    const int tid  = threadIdx.x;
    const int wave = tid >> 6;
    const int lane = tid & 63;
    const int half = lane >> 5;          // query within the pass
    const int hl   = lane & 31;          // neighbor slot

    // wave-uniform kernel points -> SGPRs via s_load
    float kp[K * 3];
    #pragma unroll
    for (int i = 0; i < K * 3; ++i) kp[i] = kpts[i];

    const int qBase = (blockIdx.x * WAVES + wave) * QPW;

    int c0 = 0, c1 = 0, c2 = 0, c3 = 0;  // active counts, wave-uniform

    // ---- Phase A: two passes, each pass = 2 queries x 32 neighbors ----
    #pragma unroll
    for (int p = 0; p < 2; ++p) {
        const int m = qBase + p * 2 + half;
        float infl = 0.0f;
        int   packed = 0;
        if (m < N) {
            const int idx = inds[m * H + hl];    // coalesced 128B per half
            if (idx >= 0 && idx < N) {
                const float qx = q_pts[m * 3 + 0];
                const float qy = q_pts[m * 3 + 1];
                const float qz = q_pts[m * 3 + 2];
                const float nx = s_pts[idx * 3 + 0] - qx;
                const float ny = s_pts[idx * 3 + 1] - qy;
                const float nz = s_pts[idx * 3 + 2] - qz;
                float best = 1e30f;
                int   kbest = 0;
                #pragma unroll
                for (int k = 0; k < K; ++k) {    // math bit-identical to R4
                    const float dx = nx - kp[k * 3 + 0];
                    const float dy = ny - kp[k * 3 + 1];
                    const float dz = nz - kp[k * 3 + 2];
                    const float d2 = dx * dx + dy * dy + dz * dz;
                    if (d2 < best) { best = d2; kbest = k; }
                }
                infl = 1.0f - __builtin_amdgcn_sqrtf(best) * (1.0f / SIGMA);
                if (infl < 0.0f) infl = 0.0f;
                packed = idx | (kbest << 20);
            }
        }
        const unsigned long long ball = __ballot(infl > 0.0f);
        const unsigned int lo = (unsigned int)(ball & 0xFFFFFFFFu);
        const unsigned int hi = (unsigned int)(ball >> 32);
        const unsigned int maskH = half ? hi : lo;
        const int rank = __popc(maskH & ((1u << hl) - 1u));
        if (infl > 0.0f)
            list[wave][p * 2 + half][rank] = make_float2(__int_as_float(packed), infl);
        if (p == 0) { c0 = __popc(lo); c1 = __popc(hi); }
        else        { c2 = __popc(lo); c3 = __popc(hi); }
    }
    // same-wave LDS RAW: DS pipe is in-order per wave; no barrier needed.

    // ---- Phase B: quarter-wave per query, float4 channels, 2 pops/iter ----
    const int q  = lane >> 4;            // which of the 4 queries
    const int ql = lane & 15;            // channel group (4 channels)
    const int cq = (q < 2) ? (q == 0 ? c0 : c1) : (q == 2 ? c2 : c3);
    int maxc = c0 > c1 ? c0 : c1;
    if (c2 > maxc) maxc = c2;
    if (c3 > maxc) maxc = c3;

    float4 acc = make_float4(0.0f, 0.0f, 0.0f, 0.0f);
    for (int i = 0; i < maxc; i += 2) {
        if (i < cq) {
            const float4 pf = *(const float4*)&list[wave][q][i];  // 16B aligned
            const int   p0   = __float_as_int(pf.x);
            const float f0   = pf.y;
            const bool  has1 = (i + 1) < cq;
            const int   p1   = has1 ? __float_as_int(pf.z) : 0;   // row 0: hot line
            const float f1   = has1 ? pf.w : 0.0f;
            const float4 a0 = *(const float4*)(s_feats + (size_t)(p0 & 0xFFFFF) * C + ql * 4);
            const float4 w0 = *(const float4*)(weights + (p0 >> 20) * C + ql * 4);
            const float4 a1 = *(const float4*)(s_feats + (size_t)(p1 & 0xFFFFF) * C + ql * 4);
            const float4 w1 = *(const float4*)(weights + (p1 >> 20) * C + ql * 4);
            acc.x += a0.x * w0.x * f0;  acc.y += a0.y * w0.y * f0;
            acc.z += a0.z * w0.z * f0;  acc.w += a0.w * w0.w * f0;
            acc.x += a1.x * w1.x * f1;  acc.y += a1.y * w1.y * f1;
            acc.z += a1.z * w1.z * f1;  acc.w += a1.w * w1.w * f1;
        }
    }

    const int mq = qBase + q;
    if (mq < N)
        *(float4*)(out + (size_t)mq * C + ql * 4) = acc;   // 256B per query
}

extern "C" void kernel_launch(void* const* d_in, const int* in_sizes, int n_in,
                              void* d_out, int out_size, void* d_ws, size_t ws_size,
                              hipStream_t stream) {
    const float* q_pts   = (const float*)d_in[0];
    const float* s_pts   = (const float*)d_in[1];
    const float* s_feats = (const float*)d_in[2];
    const int*   inds    = (const int*)d_in[3];
    const float* weights = (const float*)d_in[4];
    const float* kpts    = (const float*)d_in[5];
    float* out = (float*)d_out;

    const int N = in_sizes[0] / 3;               // q_pts is (N,3)
    const int qpb = WAVES * QPW;                 // 16 queries per block
    const int blocks = (N + qpb - 1) / qpb;      // 6250
    kpconv_kernel<<<blocks, 256, 0, stream>>>(q_pts, s_pts, s_feats, inds,
                                              weights, kpts, out, N);
}